// Round 3
// baseline (117.947 us; speedup 1.0000x reference)
//
#include <hip/hip_runtime.h>
#include <math.h>

// Problem constants (from reference setup_inputs)
#define NQ 2048
#define NB 8192
#define DIM 32

#define LOG2E 1.44269504088896340736f

typedef _Float16 half8 __attribute__((ext_vector_type(8)));
typedef float    f32x4 __attribute__((ext_vector_type(4)));

// ---------------- workspace layout (bytes, 64-B aligned) ----------------
#define WS_ACC 0         // 2*NQ f32 (16384 B)
#define WS_Q2  16448     // NQ f32
#define WS_B2  24640     // NB f32
#define WS_XQH 57408     // NQ*DIM f16   (xq*w rounded)
#define WS_XBH 188480    // NB*DIM f16   (-2*(xb*w) rounded-then-scaled)

// Pre: convert rows to f16 with norms computed FROM THE ROUNDED VALUES
// (so mfma d2 = ||a-b||^2 has no representation-mismatch cancellation).
// XBh is stored pre-scaled by -2 (exact: exponent+1 + sign) so the main
// MFMA with C = q2+b2 emits d2 directly.
__global__ __launch_bounds__(256) void relnw_pre(
    const float* __restrict__ xq, const float* __restrict__ xb,
    const float* __restrict__ w,
    _Float16* __restrict__ XQh, _Float16* __restrict__ XBh,
    float* __restrict__ q2, float* __restrict__ b2,
    float* __restrict__ acc)
{
    const int tid = threadIdx.x;
    const int gi  = blockIdx.x * 256 + tid;
    if (gi < 2 * NQ) acc[gi] = 0.f;      // zero atomic accumulators

    const int row = blockIdx.x * 64 + (tid >> 2);
    const int p   = tid & 3;             // 8-elem chunk within the row
    if (row >= NQ + NB) return;

    const float* src; _Float16* dst; float* s2; float scale;
    if (row < NQ) { src = xq + (size_t)row * DIM;
                    dst = XQh + (size_t)row * DIM; s2 = q2 + row; scale = 1.f; }
    else          { int j = row - NQ;
                    src = xb + (size_t)j * DIM;
                    dst = XBh + (size_t)j * DIM;   s2 = b2 + j;   scale = -2.f; }

    const float4 xa  = ((const float4*)src)[p * 2];
    const float4 xbv = ((const float4*)src)[p * 2 + 1];
    const float4 wa  = ((const float4*)w)[p * 2];
    const float4 wb  = ((const float4*)w)[p * 2 + 1];
    const float xs[8]  = {xa.x, xa.y, xa.z, xa.w, xbv.x, xbv.y, xbv.z, xbv.w};
    const float ws_[8] = {wa.x, wa.y, wa.z, wa.w, wb.x, wb.y, wb.z, wb.w};

    half8 h;
    float s = 0.f;
#pragma unroll
    for (int c = 0; c < 8; ++c) {
        float t = xs[c] * ws_[c];
        _Float16 hh = (_Float16)t;       // the rounding
        float th = (float)hh;
        s = fmaf(th, th, s);             // norm of the ROUNDED vector
        h[c] = (_Float16)(th * scale);   // exact scaling
    }
    *(half8*)(dst + p * 8) = h;          // coalesced 16-B store

    // row-norm: reduce over the 4 chunk-lanes (low 2 lane bits)
    s += __shfl_xor(s, 1, 64);
    s += __shfl_xor(s, 2, 64);
    if (p == 0) *s2 = s;
}

// Main: grid (8, 128) = 1024 blocks (4/CU resident), 256 threads (4 waves).
// Wave task: one 16-query tile x 256-bg chunk = 16 MFMA tiles.
//
// R9 (swapped operands): mfma(A=XBh rows, B=XQh) so D[row=bg, col=query]:
// lane(quad,m) holds d2 for bg = it*16+quad*4+g (g=reg), query = q0+m.
// The 4 accumulator regs now span 4 CONSECUTIVE bg columns of ONE r row
// => r is loaded as one aligned float4 per lane per iteration (1 VMEM
// instr, 1 KB/wave) instead of 4 scalar dwords. R2's counters showed main
// at ~2.6 TB/s on the r stream (vs 6.3 achievable) with VALU ~3us: the
// scalar dword gather was memory-parallelism-bound, not BW- or VALU-bound.
// yb/b2 become float4 broadcasts, q2 one scalar, final reduce 2 shuffles.
// Per-element math identical (same dots, same C) -> absmax unchanged.
//
// A-frag: lane(quad,m) = XBh[bstart+it*16+m][quad*8..+7]  (per iter)
// B-frag: lane(quad,m) = XQh[q0+m][quad*8..+7]            (fixed)
// r ring 8 deep (~960cy cover); ops (afrag/yv4/b24) 3-slot, 2 iters ahead
// (~230cy, covers L2). All ring indices constant under full unroll.
//
// R8 lesson (keep): __launch_bounds__(256,2) — (256,4) caps VGPR at 64 and
// spills the whole pipeline (37 MB scratch traffic). ~102 VGPR here.
// R5 lesson (keep): no __threadfence / fused finalize.
#define BT_PER_WAVE 16
#define BG_PER_WAVE (BT_PER_WAVE * 16)   // 256

__global__ __launch_bounds__(256, 2) void relnw_main(
    const _Float16* __restrict__ XQh,  // (NQ, DIM)
    const _Float16* __restrict__ XBh,  // (NB, DIM), pre-scaled by -2
    const float* __restrict__ q2,      // (NQ,)
    const float* __restrict__ b2,      // (NB,)
    const float* __restrict__ yb,      // (NB,)
    const float* __restrict__ r,       // (NQ, NB)
    const float* __restrict__ sigma,   // (1,)
    const float* __restrict__ rscale,  // (1,)
    float* __restrict__ acc)           // [0:NQ]=sum_k, [NQ:2NQ]=sum_k*y
{
    const int tid  = threadIdx.x;
    const int lane = tid & 63;
    const int wid  = tid >> 6;
    const int m    = lane & 15;   // query col (D) / A-row feeder / B-col feeder
    const int quad = lane >> 4;   // 0..3 (k-chunk for frags, bg-quad for D rows)

    const int q0     = blockIdx.y * 16;
    const int bstart = (blockIdx.x * 4 + wid) * BG_PER_WAVE;

    const float c1 = -LOG2E / sigma[0];   // coeff on dist (log2 space)
    const float c2 =  LOG2E * rscale[0];  // coeff on r

    // B operand: this wave's 16 queries (fixed across the bg loop)
    const half8 qfrag = *(const half8*)(XQh + (size_t)(q0 + m) * DIM + quad * 8);
    const float q2s   = q2[q0 + m];

    const _Float16* xbp = XBh + (size_t)(bstart + m) * DIM + quad * 8;
    const float*    rp  = r  + (size_t)(q0 + m) * NB + bstart + quad * 4;
    const float*    ybp = yb + bstart + quad * 4;
    const float*    b2p = b2 + bstart + quad * 4;

    float sk = 0.f, sky = 0.f;

    // prefetch rings — all indices constant-fold under full unroll
    f32x4 rrb[8];
    half8 af[3];
    f32x4 yv[3], bb[3];

    // prologue: ops for it=0,1 first (oldest retire first, so consuming
    // them never drains the younger r ring), then 8 r-iterations in flight
#pragma unroll
    for (int i = 0; i < 2; ++i) {
        af[i] = *(const half8*)(xbp + (size_t)i * 16 * DIM);
        yv[i] = *(const f32x4*)(ybp + i * 16);
        bb[i] = *(const f32x4*)(b2p + i * 16);
    }
#pragma unroll
    for (int i = 0; i < 8; ++i)
        rrb[i] = *(const f32x4*)(rp + i * 16);

#pragma unroll
    for (int it = 0; it < 16; ++it) {
        const int cs = it % 3;        // ops slot consumed this iteration
        const int ns = (it + 2) % 3;  // slot refilled with it+2 (last used it-1)
        if (it + 2 < 16) {
            af[ns] = *(const half8*)(xbp + (size_t)(it + 2) * 16 * DIM);
            yv[ns] = *(const f32x4*)(ybp + (it + 2) * 16);
            bb[ns] = *(const f32x4*)(b2p + (it + 2) * 16);
        }

        f32x4 cin;
#pragma unroll
        for (int g = 0; g < 4; ++g) cin[g] = q2s + bb[cs][g];

        // D = q2 + b2 - 2*dot = d2 ; rows = bg, cols = query
        f32x4 d2v = __builtin_amdgcn_mfma_f32_16x16x32_f16(
            af[cs], qfrag, cin, 0, 0, 0);

        const int rs = it & 7;
#pragma unroll
        for (int g = 0; g < 4; ++g) {
            float d2   = fmaxf(d2v[g], 0.f);
            float dist = __builtin_amdgcn_sqrtf(d2);
            float e    = fmaf(dist, c1, rrb[rs][g] * c2); // log2 space
            float k    = __builtin_amdgcn_exp2f(e);
            sk += k;
            sky = fmaf(k, yv[cs][g], sky);
        }

        // refill r ring slot after consumption (8 iterations of cover)
        if (it + 8 < 16)
            rrb[rs] = *(const f32x4*)(rp + (it + 8) * 16);
    }

    // All 4 values of a lane belong to query q0+m; reduce across quads.
    sk  += __shfl_xor(sk, 16, 64);
    sk  += __shfl_xor(sk, 32, 64);
    sky += __shfl_xor(sky, 16, 64);
    sky += __shfl_xor(sky, 32, 64);
    if (lane < 16) {
        atomicAdd(acc + (q0 + m),      sk);
        atomicAdd(acc + NQ + (q0 + m), sky);
    }
}

__global__ __launch_bounds__(256) void relnw_finalize(
    const float* __restrict__ acc, float* __restrict__ out)
{
    int q = blockIdx.x * 256 + threadIdx.x;
    if (q < NQ)
        out[q] = acc[NQ + q] / (acc[q] + 1e-8f);
}

extern "C" void kernel_launch(void* const* d_in, const int* in_sizes, int n_in,
                              void* d_out, int out_size, void* d_ws, size_t ws_size,
                              hipStream_t stream) {
    const float* xb     = (const float*)d_in[0]; // (8192,32)
    const float* yb     = (const float*)d_in[1]; // (8192,)
    const float* xq     = (const float*)d_in[2]; // (2048,32)
    const float* r      = (const float*)d_in[3]; // (2048,8192)
    const float* sigma  = (const float*)d_in[4]; // (1,)
    const float* rscale = (const float*)d_in[5]; // (1,)
    const float* w      = (const float*)d_in[6]; // (32,)
    float* out = (float*)d_out;

    char* ws = (char*)d_ws;
    float*    acc = (float*)(ws + WS_ACC);
    float*    q2  = (float*)(ws + WS_Q2);
    float*    b2  = (float*)(ws + WS_B2);
    _Float16* XQh = (_Float16*)(ws + WS_XQH);
    _Float16* XBh = (_Float16*)(ws + WS_XBH);

    relnw_pre<<<(NQ + NB) / 64, 256, 0, stream>>>(xq, xb, w, XQh, XBh, q2, b2, acc);

    dim3 grid(NB / (4 * BG_PER_WAVE), NQ / 16);  // (8, 128) = 1024 blocks
    relnw_main<<<grid, 256, 0, stream>>>(XQh, XBh, q2, b2, yb, r, sigma, rscale, acc);

    relnw_finalize<<<(NQ + 255) / 256, 256, 0, stream>>>(acc, out);
}

// Round 4
// 109.247 us; speedup vs baseline: 1.0796x; 1.0796x over previous
//
#include <hip/hip_runtime.h>
#include <math.h>

// Problem constants (from reference setup_inputs)
#define NQ 2048
#define NB 8192
#define DIM 32

#define LOG2E 1.44269504088896340736f

typedef _Float16 half8 __attribute__((ext_vector_type(8)));
typedef float    f32x4 __attribute__((ext_vector_type(4)));

// ---------------- workspace layout (bytes, 64-B aligned) ----------------
#define WS_ACC 0         // 2*NQ f32 (16384 B)
#define WS_Q2  16448     // NQ f32
#define WS_B2  24640     // NB f32
#define WS_XQH 57408     // NQ*DIM f16   (xq*w rounded)
#define WS_XBH 188480    // NB*DIM f16   (-2*(xb*w) rounded-then-scaled)

// Pre: convert rows to f16 with norms computed FROM THE ROUNDED VALUES
// (so mfma d2 = ||a-b||^2 has no representation-mismatch cancellation).
// XBh is stored pre-scaled by -2 (exact: exponent+1 + sign) so the main
// MFMA with C = q2+b2 emits d2 directly.
__global__ __launch_bounds__(256) void relnw_pre(
    const float* __restrict__ xq, const float* __restrict__ xb,
    const float* __restrict__ w,
    _Float16* __restrict__ XQh, _Float16* __restrict__ XBh,
    float* __restrict__ q2, float* __restrict__ b2,
    float* __restrict__ acc)
{
    const int tid = threadIdx.x;
    const int gi  = blockIdx.x * 256 + tid;
    if (gi < 2 * NQ) acc[gi] = 0.f;      // zero atomic accumulators

    const int row = blockIdx.x * 64 + (tid >> 2);
    const int p   = tid & 3;             // 8-elem chunk within the row
    if (row >= NQ + NB) return;

    const float* src; _Float16* dst; float* s2; float scale;
    if (row < NQ) { src = xq + (size_t)row * DIM;
                    dst = XQh + (size_t)row * DIM; s2 = q2 + row; scale = 1.f; }
    else          { int j = row - NQ;
                    src = xb + (size_t)j * DIM;
                    dst = XBh + (size_t)j * DIM;   s2 = b2 + j;   scale = -2.f; }

    const float4 xa  = ((const float4*)src)[p * 2];
    const float4 xbv = ((const float4*)src)[p * 2 + 1];
    const float4 wa  = ((const float4*)w)[p * 2];
    const float4 wb  = ((const float4*)w)[p * 2 + 1];
    const float xs[8]  = {xa.x, xa.y, xa.z, xa.w, xbv.x, xbv.y, xbv.z, xbv.w};
    const float ws_[8] = {wa.x, wa.y, wa.z, wa.w, wb.x, wb.y, wb.z, wb.w};

    half8 h;
    float s = 0.f;
#pragma unroll
    for (int c = 0; c < 8; ++c) {
        float t = xs[c] * ws_[c];
        _Float16 hh = (_Float16)t;       // the rounding
        float th = (float)hh;
        s = fmaf(th, th, s);             // norm of the ROUNDED vector
        h[c] = (_Float16)(th * scale);   // exact scaling
    }
    *(half8*)(dst + p * 8) = h;          // coalesced 16-B store

    // row-norm: reduce over the 4 chunk-lanes (low 2 lane bits)
    s += __shfl_xor(s, 1, 64);
    s += __shfl_xor(s, 2, 64);
    if (p == 0) *s2 = s;
}

// Main: grid (8, 128) = 1024 blocks (4/CU resident), 256 threads (4 waves).
// Wave task: one 16-query tile x 256-bg chunk = 16 MFMA tiles (2 halves of 8).
//
// R10: R0/R2/R3 all pinned main at ~2.5 TB/s on the r stream regardless of
// register-level schedule => the limiter is the DRAM request SHAPE: 16
// scattered 64-B segments per wave-load (16 query rows, 32 KB apart) runs
// at ~40% DRAM efficiency. Fix: stage r via global_load_lds — each
// instruction reads two 512-B CONTIGUOUS row segments (lanes 0-31 row 2j,
// lanes 32-63 row 2j+1), the same burst shape as the 6.5 TB/s fills.
// Epilogue reads r from LDS (ds_read_b128). gl_lds writes LDS linearly
// (lane*16), so the bank-conflict swizzle byte^=((row&7)<<4) is applied on
// the GLOBAL source address (both-sides-or-neither); read addr
// m*512 + ((it*64+quad*16)^swz) recovers global byte it*64+quad*16 of row
// m exactly (bijective), and each 8-lane b128 service group hits 8 distinct
// 16-B chunk slots -> conflict-free. yb/b2 staged too (2 KB/wave; reads are
// quad-broadcast = free). XBh frags stay global (L2-warm), reloaded per
// half BEFORE the next gl_lds batch so no vmcnt wait ever forces an
// in-flight HBM batch to drain. Explicit vmcnt(0)/lgkmcnt(0) asm +
// sched_barrier(0) at the 2 transitions (compiler can't see the gl_lds <->
// ds_read dependence). LDS 40 KB/block -> 4 blocks/CU, 16 waves/CU kept.
// Math identical to R3 (same dots, same C) -> absmax unchanged.
//
// R8 lesson (keep): __launch_bounds__(256,2) — (256,4) caps VGPR at 64 and
// spills everything. R5 lesson (keep): no __threadfence / fused finalize.
#define BT_PER_WAVE 16
#define BG_PER_WAVE (BT_PER_WAVE * 16)   // 256

#define GLDS(GSRC, LDST)                                                    \
  __builtin_amdgcn_global_load_lds(                                         \
      (const __attribute__((address_space(1))) void*)(GSRC),                \
      (__attribute__((address_space(3))) void*)(LDST), 16, 0, 0)

#define WAIT_VM0                                                            \
  { asm volatile("s_waitcnt vmcnt(0)" ::: "memory");                        \
    __builtin_amdgcn_sched_barrier(0); }
#define WAIT_LGKM0                                                          \
  { asm volatile("s_waitcnt lgkmcnt(0)" ::: "memory");                      \
    __builtin_amdgcn_sched_barrier(0); }

__global__ __launch_bounds__(256, 2) void relnw_main(
    const _Float16* __restrict__ XQh,  // (NQ, DIM)
    const _Float16* __restrict__ XBh,  // (NB, DIM), pre-scaled by -2
    const float* __restrict__ q2,      // (NQ,)
    const float* __restrict__ b2,      // (NB,)
    const float* __restrict__ yb,      // (NB,)
    const float* __restrict__ r,       // (NQ, NB)
    const float* __restrict__ sigma,   // (1,)
    const float* __restrict__ rscale,  // (1,)
    float* __restrict__ acc)           // [0:NQ]=sum_k, [NQ:2NQ]=sum_k*y
{
    // LDS: per wave: 8 KB r half-buffer; per block: +4x1KB b2, +4x1KB yb
    __shared__ char lds[4 * 8192 + 4 * 1024 + 4 * 1024];  // 40960 B

    const int tid  = threadIdx.x;
    const int lane = tid & 63;
    const int wid  = tid >> 6;
    const int m    = lane & 15;   // query col (D) / A-row feeder
    const int quad = lane >> 4;   // 0..3 (k-chunk for frags, bg-quad for D rows)

    const int q0     = blockIdx.y * 16;
    const int bstart = (blockIdx.x * 4 + wid) * BG_PER_WAVE;

    char*  waveR = lds + wid * 8192;
    float* b2l   = (float*)(lds + 32768 + wid * 1024);
    float* ybl   = (float*)(lds + 36864 + wid * 1024);

    const float c1 = -LOG2E / sigma[0];   // coeff on dist (log2 space)
    const float c2 =  LOG2E * rscale[0];  // coeff on r

    // B operand: this wave's 16 queries (fixed across the bg loop)
    const half8 qfrag = *(const half8*)(XQh + (size_t)(q0 + m) * DIM + quad * 8);
    const float q2s   = q2[q0 + m];
    const int   swz   = (m & 7) << 4;

    // ---- stage aux: b2/yb chunk (1 KB each, linear) ----
    GLDS((const char*)(b2 + bstart) + lane * 16, b2l);
    GLDS((const char*)(yb + bstart) + lane * 16, ybl);

    // ---- r stage source pointers: instr j covers rows 2j (lanes 0-31)
    //      and 2j+1 (lanes 32-63), 512 B contiguous each; the XOR on the
    //      source pre-applies the LDS read swizzle (gl_lds dest is linear).
    const int jj = lane >> 5;          // row parity within instruction
    const int cc = lane & 31;          // 16-B chunk within the 512-B segment
    const char* rsrc[8];
#pragma unroll
    for (int j = 0; j < 8; ++j) {
        const int rw = 2 * j + jj;
        rsrc[j] = (const char*)(r + (size_t)(q0 + rw) * NB + bstart)
                  + ((cc * 16) ^ ((rw & 7) << 4));
    }

    // ---- stage r half 0 (8 KB, eight 1-KB bursts) ----
#pragma unroll
    for (int j = 0; j < 8; ++j) GLDS(rsrc[j], waveR + j * 1024);

    // ---- A fragments for half 0 (XBh, L2-warm) ----
    half8 af[8];
#pragma unroll
    for (int i = 0; i < 8; ++i)
        af[i] = *(const half8*)(XBh + (size_t)(bstart + i * 16 + m) * DIM + quad * 8);

    float sk = 0.f, sky = 0.f;

    WAIT_VM0  // aux + r half0 + af all resident

#pragma unroll
    for (int h = 0; h < 2; ++h) {
        if (h == 1) {
            // reload A frags for half 1 FIRST (older than the gl_lds batch,
            // so consuming them later never forces an HBM drain)
#pragma unroll
            for (int i = 0; i < 8; ++i)
                af[i] = *(const half8*)(XBh +
                        (size_t)(bstart + 128 + i * 16 + m) * DIM + quad * 8);
            WAIT_LGKM0  // all half-0 LDS reads done -> safe to overwrite
#pragma unroll
            for (int j = 0; j < 8; ++j) GLDS(rsrc[j] + 512, waveR + j * 1024);
            WAIT_VM0    // half-1 r staged (af retired too)
        }

#pragma unroll
        for (int it = 0; it < 8; ++it) {
            const int co = h * 128 + it * 16 + quad * 4;       // bg chunk offset
            const f32x4 bb = *(const f32x4*)(b2l + co);        // broadcast read
            const f32x4 yv = *(const f32x4*)(ybl + co);        // broadcast read
            const f32x4 rr = *(const f32x4*)(waveR + m * 512 +
                                 ((it * 64 + quad * 16) ^ swz));

            f32x4 cin;
#pragma unroll
            for (int g = 0; g < 4; ++g) cin[g] = q2s + bb[g];

            // D = q2 + b2 - 2*dot = d2 ; rows = bg, cols = query
            const f32x4 d2v = __builtin_amdgcn_mfma_f32_16x16x32_f16(
                af[it], qfrag, cin, 0, 0, 0);

#pragma unroll
            for (int g = 0; g < 4; ++g) {
                float d2   = fmaxf(d2v[g], 0.f);
                float dist = __builtin_amdgcn_sqrtf(d2);
                float e    = fmaf(dist, c1, rr[g] * c2);  // log2 space
                float k    = __builtin_amdgcn_exp2f(e);
                sk += k;
                sky = fmaf(k, yv[g], sky);
            }
        }
    }

    // All 4 values of a lane belong to query q0+m; reduce across quads.
    sk  += __shfl_xor(sk, 16, 64);
    sk  += __shfl_xor(sk, 32, 64);
    sky += __shfl_xor(sky, 16, 64);
    sky += __shfl_xor(sky, 32, 64);
    if (lane < 16) {
        atomicAdd(acc + (q0 + m),      sk);
        atomicAdd(acc + NQ + (q0 + m), sky);
    }
}

__global__ __launch_bounds__(256) void relnw_finalize(
    const float* __restrict__ acc, float* __restrict__ out)
{
    int q = blockIdx.x * 256 + threadIdx.x;
    if (q < NQ)
        out[q] = acc[NQ + q] / (acc[q] + 1e-8f);
}

extern "C" void kernel_launch(void* const* d_in, const int* in_sizes, int n_in,
                              void* d_out, int out_size, void* d_ws, size_t ws_size,
                              hipStream_t stream) {
    const float* xb     = (const float*)d_in[0]; // (8192,32)
    const float* yb     = (const float*)d_in[1]; // (8192,)
    const float* xq     = (const float*)d_in[2]; // (2048,32)
    const float* r      = (const float*)d_in[3]; // (2048,8192)
    const float* sigma  = (const float*)d_in[4]; // (1,)
    const float* rscale = (const float*)d_in[5]; // (1,)
    const float* w      = (const float*)d_in[6]; // (32,)
    float* out = (float*)d_out;

    char* ws = (char*)d_ws;
    float*    acc = (float*)(ws + WS_ACC);
    float*    q2  = (float*)(ws + WS_Q2);
    float*    b2  = (float*)(ws + WS_B2);
    _Float16* XQh = (_Float16*)(ws + WS_XQH);
    _Float16* XBh = (_Float16*)(ws + WS_XBH);

    relnw_pre<<<(NQ + NB) / 64, 256, 0, stream>>>(xq, xb, w, XQh, XBh, q2, b2, acc);

    dim3 grid(NB / (4 * BG_PER_WAVE), NQ / 16);  // (8, 128) = 1024 blocks
    relnw_main<<<grid, 256, 0, stream>>>(XQh, XBh, q2, b2, yb, r, sigma, rscale, acc);

    relnw_finalize<<<(NQ + 255) / 256, 256, 0, stream>>>(acc, out);
}